// Round 3
// baseline (54433.179 us; speedup 1.0000x reference)
//
#include <hip/hip_runtime.h>
#include <stdint.h>

#define NBATCH 16
#define GRP 128
#define RADIX 1024
#define SC_TILE 2048   // 64 lanes * 32 items, single-wave blocks
#define SC_ITEMS 32
#define NKB 256        // grid-stride blocks for key kernels

typedef unsigned long long ull;

// ---------------- setup ----------------

__global__ void find_starts(const int* __restrict__ coords, int n,
                            int* __restrict__ start /*17*/) {
  const int i = blockIdx.x * 256 + threadIdx.x;
  if (i >= n) return;
  const int b = coords[4 * i];
  if (i == 0) {
    for (int v = 0; v <= b; ++v) start[v] = 0;
  }
  if (i == n - 1) {
    for (int v = b + 1; v <= NBATCH; ++v) start[v] = n;
  } else {
    const int b2 = coords[4 * (i + 1)];
    if (b2 != b)
      for (int v = b + 1; v <= b2; ++v) start[v] = i + 1;
  }
}

__global__ void prefix16(const int* __restrict__ bs_in, int* __restrict__ bs,
                         int* __restrict__ bsp, int* __restrict__ num,
                         int* __restrict__ nump) {
  if (threadIdx.x == 0 && blockIdx.x == 0) {
    int b = 0;
    for (int i = 0; i < NBATCH; ++i) {
      const int s = bs_in[i];
      const int ni = bs_in[i + 1] - s;
      bs[i] = s; bsp[i] = b;
      num[i] = ni;
      const int npi = (ni + GRP - 1) / GRP * GRP;
      nump[i] = npi;
      b += npi;
    }
    bs[NBATCH] = bs_in[NBATCH];
    bsp[NBATCH] = b;
  }
}

__device__ __forceinline__ unsigned int window_key(const int4 c, int sz, int sy,
                                                   int sx, int mode) {
  const int b = c.x, z = c.y, y = c.z, x = c.w;
  const int mx = ((sx + 15) >> 4) + 1;
  const int my = ((sy + 15) >> 4) + 1;
  const int mz = ((sz + 7) >> 3) + 1;
  const int mper = mx * my * mz;
  const int wcx = x >> 4, cix = x & 15;
  const int wcy = y >> 4, ciy = y & 15;
  const int wcz = z >> 3, ciz = z & 7;
  if (mode == 0) {
    const int bwin = b * mper + wcx * (my * mz) + wcy * mz + wcz;
    return (unsigned int)(bwin * 2048 + cix * 128 + ciy * 8 + ciz);
  } else {
    const int bwin = b * mper + wcy * (mx * mz) + wcx * mz + wcz;
    return (unsigned int)(bwin * 2048 + ciy * 128 + cix * 8 + ciz);
  }
}

// keys (mode 0) + win2flat + flat2win + 3-pass global histogram, grid-stride
__global__ void keys_x_fused(const int* __restrict__ coords,
                             const int* __restrict__ shape,
                             const int* __restrict__ bs, const int* __restrict__ bsp,
                             const int* __restrict__ num, const int* __restrict__ nump,
                             ull* __restrict__ keys, int* __restrict__ win2flat,
                             int* __restrict__ f2w, unsigned int* __restrict__ ghist,
                             int n, int n_p) {
  __shared__ int sbs[NBATCH + 1], sbsp[NBATCH + 1], snum[NBATCH], snump[NBATCH];
  __shared__ unsigned int h[3 * RADIX];
  const int tid = threadIdx.x;
  if (tid <= NBATCH) { sbs[tid] = bs[tid]; sbsp[tid] = bsp[tid]; }
  if (tid < NBATCH) { snum[tid] = num[tid]; snump[tid] = nump[tid]; }
  for (int d = tid; d < 3 * RADIX; d += 256) h[d] = 0;
  __syncthreads();
  const int sz = shape[0], sy = shape[1], sx = shape[2];
  const int nmax = (n > n_p) ? n : n_p;
  const int stride = NKB * 256;
  for (int i = blockIdx.x * 256 + tid; i < nmax; i += stride) {
    if (i < n) {
      const int4 c = ((const int4*)coords)[i];
      const unsigned int key = window_key(c, sz, sy, sx, 0);
      keys[i] = ((ull)key << 32) | (unsigned int)i;
      win2flat[i] = i + (sbsp[c.x] - sbs[c.x]);
      atomicAdd(&h[key & 1023], 1u);
      atomicAdd(&h[RADIX + ((key >> 10) & 1023)], 1u);
      atomicAdd(&h[2 * RADIX + (key >> 20)], 1u);
    }
    if (i < n_p) {
      const int k = i;
      int b = 0;
#pragma unroll
      for (int j = 1; j < NBATCH; ++j) b += (k >= sbsp[j]) ? 1 : 0;
      const int bias = sbsp[b] - sbs[b];
      const int nb = snum[b], npb = snump[b];
      int val = k - bias;
      if (nb != npb && k >= sbsp[b] + nb) {
        if (npb != GRP) {
          val = k - GRP - bias;
        } else {
          const int m = nb > 1 ? nb : 1;
          val = sbs[b] + (k - sbsp[b] - nb) % m;
        }
      }
      f2w[k] = val;
    }
  }
  __syncthreads();
  for (int d = tid; d < 3 * RADIX; d += 256) {
    const unsigned int v = h[d];
    if (v) atomicAdd(&ghist[d], v);
  }
}

__global__ void keys_y_fused(const int* __restrict__ coords,
                             const int* __restrict__ shape,
                             ull* __restrict__ keys,
                             unsigned int* __restrict__ ghist, int n) {
  __shared__ unsigned int h[3 * RADIX];
  const int tid = threadIdx.x;
  for (int d = tid; d < 3 * RADIX; d += 256) h[d] = 0;
  __syncthreads();
  const int sz = shape[0], sy = shape[1], sx = shape[2];
  const int stride = NKB * 256;
  for (int i = blockIdx.x * 256 + tid; i < n; i += stride) {
    const int4 c = ((const int4*)coords)[i];
    const unsigned int key = window_key(c, sz, sy, sx, 1);
    keys[i] = ((ull)key << 32) | (unsigned int)i;
    atomicAdd(&h[key & 1023], 1u);
    atomicAdd(&h[RADIX + ((key >> 10) & 1023)], 1u);
    atomicAdd(&h[2 * RADIX + (key >> 20)], 1u);
  }
  __syncthreads();
  for (int d = tid; d < 3 * RADIX; d += 256) {
    const unsigned int v = h[d];
    if (v) atomicAdd(&ghist[d], v);
  }
}

// exclusive scan of each of the 3 rows of ghist -> gbase
__device__ __forceinline__ unsigned int block_scan_excl(unsigned int thread_sum,
                                                        unsigned int* s) {
  const int tid = threadIdx.x;
  s[tid] = thread_sum;
  __syncthreads();
#pragma unroll
  for (int off = 1; off < 256; off <<= 1) {
    unsigned int x = (tid >= off) ? s[tid - off] : 0u;
    __syncthreads();
    s[tid] += x;
    __syncthreads();
  }
  return s[tid] - thread_sum;
}

__global__ void scan_hist(const unsigned int* __restrict__ ghist,
                          unsigned int* __restrict__ gbase) {
  __shared__ unsigned int s[256];
  const int tid = threadIdx.x;
  for (int r = 0; r < 3; ++r) {
    unsigned int v[4], sum = 0;
    const int base = r * RADIX + tid * 4;
#pragma unroll
    for (int j = 0; j < 4; ++j) { v[j] = ghist[base + j]; sum += v[j]; }
    unsigned int run = block_scan_excl(sum, s);
#pragma unroll
    for (int j = 0; j < 4; ++j) { gbase[base + j] = run; run += v[j]; }
    __syncthreads();
  }
}

// ---------------- Onesweep scatter: single-wave blocks, decoupled lookback ----
// status word: [ptag:4][flag:4][value:24]  flag 1=aggregate 2=inclusive
#define FLAG_AGG (1u << 24)
#define FLAG_INC (2u << 24)

__global__ __launch_bounds__(64) void onesweep_scatter(
    const ull* __restrict__ src, ull* __restrict__ dst,
    int* __restrict__ out_idx, const unsigned int* __restrict__ gbase,
    unsigned int* __restrict__ status, int n, int shift, unsigned int ptag) {
  __shared__ ull tile[SC_TILE];
  __shared__ unsigned int h[RADIX];
  const int lane = threadIdx.x;
  const int blk = blockIdx.x;
  const int base = blk * SC_TILE;
  for (int d = lane; d < RADIX; d += 64) h[d] = 0;
  __syncthreads();
  const ull lt = (1ull << lane) - 1ull;

  // Phase A: load tile, per-block digit histogram (wave-synchronous, stable)
  for (int j0 = 0; j0 < SC_ITEMS; j0 += 8) {
    ull v[8];
#pragma unroll
    for (int u = 0; u < 8; ++u) {
      const int e = base + (j0 + u) * 64 + lane;
      v[u] = (e < n) ? src[e] : ~0ull;
    }
#pragma unroll
    for (int u = 0; u < 8; ++u) {
      tile[(j0 + u) * 64 + lane] = v[u];
      const bool valid = (base + (j0 + u) * 64 + lane) < n;
      const unsigned int d = (((unsigned int)(v[u] >> 32)) >> shift) & (RADIX - 1);
      ull m = __ballot(valid);
#pragma unroll
      for (int bbit = 0; bbit < 10; ++bbit) {
        const ull bb = __ballot((d >> bbit) & 1);
        m &= ((d >> bbit) & 1) ? bb : ~bb;
      }
      const unsigned int lr = (unsigned int)__popcll(m & lt);
      if (valid && lr == 0) atomicAdd(&h[d], (unsigned int)__popcll(m));
    }
  }
  __syncthreads();

  // publish aggregates
  unsigned int myCnt[RADIX / 64], run[RADIX / 64];
#pragma unroll
  for (int t = 0; t < RADIX / 64; ++t) {
    const int d = lane + t * 64;
    myCnt[t] = h[d];
    __hip_atomic_store(&status[(size_t)blk * RADIX + d],
                       (ptag << 28) | FLAG_AGG | myCnt[t],
                       __ATOMIC_RELEASE, __HIP_MEMORY_SCOPE_AGENT);
  }
  // lookback
#pragma unroll
  for (int t = 0; t < RADIX / 64; ++t) {
    const int d = lane + t * 64;
    unsigned int sum = 0;
    int j = blk - 1;
    while (j >= 0) {
      unsigned int w;
      do {
        w = __hip_atomic_load(&status[(size_t)j * RADIX + d],
                              __ATOMIC_ACQUIRE, __HIP_MEMORY_SCOPE_AGENT);
      } while ((w >> 28) != ptag);
      sum += w & 0xFFFFFFu;
      if (w & FLAG_INC) break;
      --j;
    }
    run[t] = sum;
  }
#pragma unroll
  for (int t = 0; t < RADIX / 64; ++t) {
    const int d = lane + t * 64;
    __hip_atomic_store(&status[(size_t)blk * RADIX + d],
                       (ptag << 28) | FLAG_INC | (run[t] + myCnt[t]),
                       __ATOMIC_RELEASE, __HIP_MEMORY_SCOPE_AGENT);
  }
  __syncthreads();
#pragma unroll
  for (int t = 0; t < RADIX / 64; ++t) {
    const int d = lane + t * 64;
    h[d] = gbase[d] + run[t];
  }
  __syncthreads();

  // Phase C: stable scatter (wave-synchronous rank per digit)
  for (int j = 0; j < SC_ITEMS; ++j) {
    const int e = base + j * 64 + lane;
    const bool valid = e < n;
    const ull p = tile[j * 64 + lane];
    const unsigned int d = (((unsigned int)(p >> 32)) >> shift) & (RADIX - 1);
    ull m = __ballot(valid);
#pragma unroll
    for (int bbit = 0; bbit < 10; ++bbit) {
      const ull bb = __ballot((d >> bbit) & 1);
      m &= ((d >> bbit) & 1) ? bb : ~bb;
    }
    const unsigned int lr = (unsigned int)__popcll(m & lt);
    const unsigned int cnt = (unsigned int)__popcll(m);
    const int leaderLane = valid ? (int)__builtin_ctzll(m) : 0;
    unsigned int old = 0;
    if (valid && lr == 0) old = atomicAdd(&h[d], cnt);
    old = __shfl(old, leaderLane, 64);
    if (valid) {
      const unsigned int pos = old + lr;
      if (out_idx) out_idx[pos] = (int)(unsigned int)p;
      else dst[pos] = p;
    }
  }
}

// ---------------- host ----------------

static inline int ceil_div(int a, int b) { return (a + b - 1) / b; }

extern "C" void kernel_launch(void* const* d_in, const int* in_sizes, int n_in,
                              void* d_out, int out_size, void* d_ws, size_t ws_size,
                              hipStream_t stream) {
  const int* coords = (const int*)d_in[0];
  const int* shape = (const int*)d_in[2];
  const int n = in_sizes[0] / 4;
  const int n_p = out_size - 3 * n;

  int* out = (int*)d_out;
  int* flat2win = out;
  int* win2flat = out + n_p;
  int* idx_x = out + (size_t)n_p + n;
  int* idx_y = out + (size_t)n_p + 2 * (size_t)n;

  const int NB = ceil_div(n, SC_TILE);

  char* ws = (char*)d_ws;
  size_t off = 0;
  auto take = [&](size_t bytes) -> void* {
    void* p = (void*)(ws + off);
    off += (bytes + 255) & ~(size_t)255;
    return p;
  };
  ull* A = (ull*)take((size_t)n * 8);
  ull* B = (ull*)take((size_t)n * 8);
  unsigned int* status = (unsigned int*)take((size_t)6 * NB * RADIX * 4);
  unsigned int* ghist = (unsigned int*)take(3 * RADIX * 4);
  unsigned int* gbase = (unsigned int*)take(3 * RADIX * 4);
  int* starts = (int*)take(128);
  int* bs = (int*)take(128);
  int* bsp = (int*)take(128);
  int* num = (int*)take(64);
  int* nump = (int*)take(64);
  (void)ws_size; (void)n_in;

  find_starts<<<ceil_div(n, 256), 256, 0, stream>>>(coords, n, starts);
  prefix16<<<1, 64, 0, stream>>>(starts, bs, bsp, num, nump);

  hipMemsetAsync(ghist, 0, 3 * RADIX * 4, stream);
  keys_x_fused<<<NKB, 256, 0, stream>>>(coords, shape, bs, bsp, num, nump,
                                        A, win2flat, flat2win, ghist, n, n_p);
  scan_hist<<<1, 256, 0, stream>>>(ghist, gbase);

  int pidx = 0;
  auto run_sort = [&](int* oidx) {
    ull* src = A;
    ull* dst = B;
    for (int pass = 0; pass < 3; ++pass) {
      onesweep_scatter<<<NB, 64, 0, stream>>>(
          src, dst, (pass == 2) ? oidx : nullptr, gbase + pass * RADIX,
          status + (size_t)pidx * NB * RADIX, n, 10 * pass,
          (unsigned int)(pidx + 1));
      ++pidx;
      ull* t = src; src = dst; dst = t;
    }
  };

  run_sort(idx_x);

  hipMemsetAsync(ghist, 0, 3 * RADIX * 4, stream);
  keys_y_fused<<<NKB, 256, 0, stream>>>(coords, shape, A, ghist, n);
  scan_hist<<<1, 256, 0, stream>>>(ghist, gbase);

  run_sort(idx_y);
}

// Round 4
// 480.299 us; speedup vs baseline: 113.3319x; 113.3319x over previous
//
#include <hip/hip_runtime.h>
#include <stdint.h>

#define NBATCH 16
#define GRP 128
#define RADIX 1024
#define TILE 2048          // elements per block: 256 threads * 8
#define TITEMS 8
#define SCAN_CHUNK 2048

typedef unsigned long long ull;

// ---------------- setup ----------------

__global__ void find_starts(const int* __restrict__ coords, int n,
                            int* __restrict__ start /*17*/) {
  const int i = blockIdx.x * 256 + threadIdx.x;
  if (i >= n) return;
  const int b = coords[4 * i];
  if (i == 0) {
    for (int v = 0; v <= b; ++v) start[v] = 0;
  }
  if (i == n - 1) {
    for (int v = b + 1; v <= NBATCH; ++v) start[v] = n;
  } else {
    const int b2 = coords[4 * (i + 1)];
    if (b2 != b)
      for (int v = b + 1; v <= b2; ++v) start[v] = i + 1;
  }
}

__global__ void prefix16(const int* __restrict__ bs_in, int* __restrict__ bs,
                         int* __restrict__ bsp, int* __restrict__ num,
                         int* __restrict__ nump) {
  if (threadIdx.x == 0 && blockIdx.x == 0) {
    int b = 0;
    for (int i = 0; i < NBATCH; ++i) {
      const int s = bs_in[i];
      const int ni = bs_in[i + 1] - s;
      bs[i] = s; bsp[i] = b;
      num[i] = ni;
      const int npi = (ni + GRP - 1) / GRP * GRP;
      nump[i] = npi;
      b += npi;
    }
    bs[NBATCH] = bs_in[NBATCH];
    bsp[NBATCH] = b;
  }
}

__device__ __forceinline__ unsigned int window_key(const int4 c, int sz, int sy,
                                                   int sx, int mode) {
  const int b = c.x, z = c.y, y = c.z, x = c.w;
  const int mx = ((sx + 15) >> 4) + 1;
  const int my = ((sy + 15) >> 4) + 1;
  const int mz = ((sz + 7) >> 3) + 1;
  const int mper = mx * my * mz;
  const int wcx = x >> 4, cix = x & 15;
  const int wcy = y >> 4, ciy = y & 15;
  const int wcz = z >> 3, ciz = z & 7;
  if (mode == 0) {
    const int bwin = b * mper + wcx * (my * mz) + wcy * mz + wcz;
    return (unsigned int)(bwin * 2048 + cix * 128 + ciy * 8 + ciz);
  } else {
    const int bwin = b * mper + wcy * (mx * mz) + wcx * mz + wcz;
    return (unsigned int)(bwin * 2048 + ciy * 128 + cix * 8 + ciz);
  }
}

// keys (mode m) + optional w2f/f2w + fused pass-0 per-block histogram.
// Block blk owns elements [blk*TILE, blk*TILE+TILE).
__global__ __launch_bounds__(256) void keys_fused(
    const int* __restrict__ coords, const int* __restrict__ shape,
    const int* __restrict__ bs, const int* __restrict__ bsp,
    const int* __restrict__ num, const int* __restrict__ nump,
    ull* __restrict__ keys, int* __restrict__ win2flat, int* __restrict__ f2w,
    unsigned int* __restrict__ counts0, int n, int n_p, int nb, int mode) {
  __shared__ int sbs[NBATCH + 1], sbsp[NBATCH + 1], snum[NBATCH], snump[NBATCH];
  __shared__ unsigned int h[RADIX];
  const int tid = threadIdx.x;
  const int blk = blockIdx.x;
  if (tid <= NBATCH) { sbs[tid] = bs[tid]; sbsp[tid] = bsp[tid]; }
  if (tid < NBATCH) { snum[tid] = num[tid]; snump[tid] = nump[tid]; }
  for (int d = tid; d < RADIX; d += 256) h[d] = 0;
  __syncthreads();
  const int sz = shape[0], sy = shape[1], sx = shape[2];
  const int base = blk * TILE;
#pragma unroll
  for (int j = 0; j < TITEMS; ++j) {
    const int i = base + j * 256 + tid;
    if (i < n) {
      const int4 c = ((const int4*)coords)[i];
      const unsigned int key = window_key(c, sz, sy, sx, mode);
      keys[i] = ((ull)key << 32) | (unsigned int)i;
      atomicAdd(&h[key & (RADIX - 1)], 1u);
      if (mode == 0) win2flat[i] = i + (sbsp[c.x] - sbs[c.x]);
    }
    if (mode == 0 && i < n_p) {
      const int k = i;
      int b = 0;
#pragma unroll
      for (int jj = 1; jj < NBATCH; ++jj) b += (k >= sbsp[jj]) ? 1 : 0;
      const int bias = sbsp[b] - sbs[b];
      const int nb2 = snum[b], npb = snump[b];
      int val = k - bias;
      if (nb2 != npb && k >= sbsp[b] + nb2) {
        if (npb != GRP) {
          val = k - GRP - bias;
        } else {
          const int m = nb2 > 1 ? nb2 : 1;
          val = sbs[b] + (k - sbsp[b] - nb2) % m;
        }
      }
      f2w[k] = val;
    }
  }
  __syncthreads();
  if (blk < nb)
    for (int d = tid; d < RADIX; d += 256)
      counts0[(size_t)d * nb + blk] = h[d];
}

// per-block digit histogram for passes 1,2
__global__ __launch_bounds__(256) void radix_hist(
    const ull* __restrict__ src, unsigned int* __restrict__ counts,
    int n, int nb, int shift) {
  __shared__ unsigned int h[RADIX];
  const int tid = threadIdx.x;
  for (int d = tid; d < RADIX; d += 256) h[d] = 0;
  __syncthreads();
  const int base = blockIdx.x * TILE;
#pragma unroll
  for (int j = 0; j < TITEMS; ++j) {
    const int e = base + j * 256 + tid;
    if (e < n) {
      const ull p = src[e];
      atomicAdd(&h[(((unsigned int)(p >> 32)) >> shift) & (RADIX - 1)], 1u);
    }
  }
  __syncthreads();
  for (int d = tid; d < RADIX; d += 256)
    counts[(size_t)d * nb + blockIdx.x] = h[d];
}

// ---------------- chained exclusive scan (in place) ----------------

__device__ __forceinline__ unsigned int block_scan_excl(unsigned int thread_sum,
                                                        unsigned int* s) {
  const int tid = threadIdx.x;
  s[tid] = thread_sum;
  __syncthreads();
#pragma unroll
  for (int off = 1; off < 256; off <<= 1) {
    unsigned int x = (tid >= off) ? s[tid - off] : 0u;
    __syncthreads();
    s[tid] += x;
    __syncthreads();
  }
  return s[tid] - thread_sum;
}

__global__ void scan_chained(unsigned int* __restrict__ data, int L,
                             unsigned long long* __restrict__ desc) {
  __shared__ unsigned int s[256];
  __shared__ unsigned int s_base;
  const int tid = threadIdx.x;
  const int blk = blockIdx.x;
  const int base = blk * SCAN_CHUNK + tid * 8;
  unsigned int v[8], sum = 0;
#pragma unroll
  for (int j = 0; j < 8; ++j) {
    const int idx = base + j;
    v[j] = (idx < L) ? data[idx] : 0u;
    sum += v[j];
  }
  const unsigned int excl = block_scan_excl(sum, s);
  const unsigned int total = s[255];
  if (tid == 0) {
    const unsigned long long tag = (blk == 0) ? (2ull << 32) : (1ull << 32);
    __hip_atomic_store(&desc[blk], tag | total, __ATOMIC_RELEASE,
                       __HIP_MEMORY_SCOPE_AGENT);
    if (blk == 0) s_base = 0;
  }
  if (blk > 0 && tid < 64) {
    unsigned int run = 0;
    int jb = blk - 1;
    for (;;) {
      const int j = jb - tid;
      unsigned long long d;
      if (j >= 0) {
        do {
          d = __hip_atomic_load(&desc[j], __ATOMIC_ACQUIRE, __HIP_MEMORY_SCOPE_AGENT);
        } while ((d >> 32) == 0);
      } else {
        d = (2ull << 32);
      }
      const unsigned long long m2 = __ballot((d >> 32) == 2);
      const int f = m2 ? __builtin_ctzll(m2) : 64;
      unsigned int contrib = (tid <= f) ? (unsigned int)d : 0u;
#pragma unroll
      for (int o = 32; o > 0; o >>= 1) contrib += __shfl_down(contrib, o, 64);
      run += __shfl(contrib, 0, 64);
      if (m2) break;
      jb -= 64;
    }
    if (tid == 0) {
      __hip_atomic_store(&desc[blk], (2ull << 32) | (run + total),
                         __ATOMIC_RELEASE, __HIP_MEMORY_SCOPE_AGENT);
      s_base = run;
    }
  }
  __syncthreads();
  unsigned int off = s_base + excl;
#pragma unroll
  for (int j = 0; j < 8; ++j) {
    const int idx = base + j;
    if (idx < L) data[idx] = off;
    off += v[j];
  }
}

// ---------------- scatter: registers + per-wave rows, 2 barriers ----------------

__global__ __launch_bounds__(256) void radix_scatter(
    const ull* __restrict__ src, ull* __restrict__ dst,
    int* __restrict__ out_idx, const unsigned int* __restrict__ counts,
    int n, int nb, int shift) {
  __shared__ unsigned int wh[4 * RADIX];
  const int tid = threadIdx.x;
  const int lane = tid & 63;
  const int w = tid >> 6;
  const int blk = blockIdx.x;
  const int base = blk * TILE + w * (TILE / 4);  // wave-contiguous chunks
  for (int d = tid; d < 4 * RADIX; d += 256) wh[d] = 0;
  __syncthreads();
  const ull lt = (1ull << lane) - 1ull;

  ull key[TITEMS];
  unsigned int meta[TITEMS];  // d(10) | lr<<10(6) | ldr<<16(6) | cnt<<22(7)
#pragma unroll
  for (int j = 0; j < TITEMS; ++j) {
    const int e = base + j * 64 + lane;
    const bool valid = e < n;
    key[j] = valid ? src[e] : 0ull;
    const unsigned int d = (((unsigned int)(key[j] >> 32)) >> shift) & (RADIX - 1);
    ull m = __ballot(valid);
#pragma unroll
    for (int bbit = 0; bbit < 10; ++bbit) {
      const ull bb = __ballot((d >> bbit) & 1);
      m &= ((d >> bbit) & 1) ? bb : ~bb;
    }
    const unsigned int lr = (unsigned int)__popcll(m & lt);
    const unsigned int cnt = (unsigned int)__popcll(m);
    const unsigned int ldr = m ? (unsigned int)__builtin_ctzll(m) : 0u;
    meta[j] = d | (lr << 10) | (ldr << 16) | (cnt << 22);
    if (valid && lr == 0) atomicAdd(&wh[w * RADIX + d], cnt);
  }
  __syncthreads();
  for (int d = tid; d < RADIX; d += 256) {
    const unsigned int c0 = wh[d];
    const unsigned int c1 = wh[RADIX + d];
    const unsigned int c2 = wh[2 * RADIX + d];
    const unsigned int g = counts[(size_t)d * nb + blk];
    wh[d] = g;
    wh[RADIX + d] = g + c0;
    wh[2 * RADIX + d] = g + c0 + c1;
    wh[3 * RADIX + d] = g + c0 + c1 + c2;
  }
  __syncthreads();
#pragma unroll
  for (int j = 0; j < TITEMS; ++j) {
    const int e = base + j * 64 + lane;
    const bool valid = e < n;
    const unsigned int mt = meta[j];
    const unsigned int d = mt & (RADIX - 1);
    const unsigned int lr = (mt >> 10) & 63u;
    const unsigned int ldr = (mt >> 16) & 63u;
    const unsigned int cnt = mt >> 22;
    unsigned int old = 0;
    if (valid && lr == 0) old = atomicAdd(&wh[w * RADIX + d], cnt);
    old = __shfl(old, (int)ldr, 64);
    if (valid) {
      const unsigned int pos = old + lr;
      if (out_idx) out_idx[pos] = (int)(unsigned int)key[j];
      else dst[pos] = key[j];
    }
  }
}

// ---------------- host ----------------

static inline int ceil_div(int a, int b) { return (a + b - 1) / b; }

extern "C" void kernel_launch(void* const* d_in, const int* in_sizes, int n_in,
                              void* d_out, int out_size, void* d_ws, size_t ws_size,
                              hipStream_t stream) {
  const int* coords = (const int*)d_in[0];
  const int* shape = (const int*)d_in[2];
  const int n = in_sizes[0] / 4;
  const int n_p = out_size - 3 * n;

  int* out = (int*)d_out;
  int* flat2win = out;
  int* win2flat = out + n_p;
  int* idx_x = out + (size_t)n_p + n;
  int* idx_y = out + (size_t)n_p + 2 * (size_t)n;

  const int NB = ceil_div(n, TILE);
  const int NBP = ceil_div((n > n_p) ? n : n_p, TILE);
  const int L = NB * RADIX;
  const int NS = ceil_div(L, SCAN_CHUNK);

  char* ws = (char*)d_ws;
  size_t off = 0;
  auto take = [&](size_t bytes) -> void* {
    void* p = (void*)(ws + off);
    off += (bytes + 255) & ~(size_t)255;
    return p;
  };
  ull* A = (ull*)take((size_t)n * 8);
  ull* B = (ull*)take((size_t)n * 8);
  unsigned int* counts = (unsigned int*)take((size_t)L * 4);
  unsigned long long* desc = (unsigned long long*)take((size_t)6 * NS * 8);
  int* starts = (int*)take(128);
  int* bs = (int*)take(128);
  int* bsp = (int*)take(128);
  int* num = (int*)take(64);
  int* nump = (int*)take(64);
  (void)ws_size; (void)n_in;

  hipMemsetAsync(desc, 0, (size_t)6 * NS * 8, stream);
  find_starts<<<ceil_div(n, 256), 256, 0, stream>>>(coords, n, starts);
  prefix16<<<1, 64, 0, stream>>>(starts, bs, bsp, num, nump);

  int scan_slice = 0;
  auto do_scan = [&]() {
    scan_chained<<<NS, 256, 0, stream>>>(counts, L, desc + (size_t)scan_slice * NS);
    ++scan_slice;
  };

  auto run_sort = [&](int mode, int* oidx) {
    keys_fused<<<NBP, 256, 0, stream>>>(coords, shape, bs, bsp, num, nump,
                                        A, win2flat, flat2win, counts,
                                        n, n_p, NB, mode);
    do_scan();
    radix_scatter<<<NB, 256, 0, stream>>>(A, B, nullptr, counts, n, NB, 0);
    radix_hist<<<NB, 256, 0, stream>>>(B, counts, n, NB, 10);
    do_scan();
    radix_scatter<<<NB, 256, 0, stream>>>(B, A, nullptr, counts, n, NB, 10);
    radix_hist<<<NB, 256, 0, stream>>>(A, counts, n, NB, 20);
    do_scan();
    radix_scatter<<<NB, 256, 0, stream>>>(A, B, oidx, counts, n, NB, 20);
  };

  run_sort(0, idx_x);
  run_sort(1, idx_y);
}